// Round 2
// baseline (118.982 us; speedup 1.0000x reference)
//
#include <hip/hip_runtime.h>
#include <stdint.h>

#define B_ROWS 1024
#define FEAT   256
#define QSZ    32768
#define SHIFT  1024
#define QX     (QSZ - B_ROWS)   // 31744
#define BM     64               // q-rows per GEMM block
#define NGY    (QSZ / BM)       // 512 blocks == partial slices per x-col
#define MARGIN 8.0f             // covers bf16 noise (~2) + key quantization (~2.5/side)

typedef float  v4f __attribute__((ext_vector_type(4)));
typedef short  v8s __attribute__((ext_vector_type(8)));

// ---------- packed score keys: orderable(m)[31:15] | j[14:0] ----------
__device__ __forceinline__ uint32_t key_flip(uint32_t u) {
    return u ^ ((uint32_t)((int32_t)u >> 31) | 0x80000000u);
}
__device__ __forceinline__ float key_m(uint32_t k) {  // floor-approx m back from key
    uint32_t u = k & 0xFFFF8000u;
    u = (u & 0x80000000u) ? (u ^ 0x80000000u) : ~u;
    return __uint_as_float(u);
}
__device__ __forceinline__ void k2_insert(uint32_t& k1, uint32_t& k2, uint32_t key) {
    uint32_t hi = max(k1, key); k1 = min(k1, key); k2 = min(k2, hi);
}
__device__ __forceinline__ uint2 k2_merge(uint2 a, uint2 b) {
    uint32_t hi = max(a.x, b.x);
    uint2 r; r.x = min(a.x, b.x); r.y = min(min(a.y, b.y), hi);
    return r;
}

// ---------- exact-score top2 (float + index tie-break, matches top_k) ----------
struct Top2 { float m1; int j1; float m2; int j2; };
__device__ __forceinline__ bool better(float ma, int ja, float mb, int jb) {
    return (ma < mb) || (ma == mb && ja < jb);
}
__device__ __forceinline__ void t2_insert(Top2& t, float m, int j) {
    if (better(m, j, t.m1, t.j1)) { t.m2 = t.m1; t.j2 = t.j1; t.m1 = m; t.j1 = j; }
    else if (better(m, j, t.m2, t.j2)) { t.m2 = m; t.j2 = j; }
}

__device__ __forceinline__ const float* q_row_ptr(int j, const float* x, const float* queue) {
    return (j < QX) ? (queue + (size_t)(j + SHIFT) * FEAT) : (x + (size_t)(j - QX) * FEAT);
}

__device__ __forceinline__ unsigned short f2bf(float f) {  // round-to-nearest-even
    uint32_t u = __float_as_uint(f);
    uint32_t r = u + 0x7FFFu + ((u >> 16) & 1u);
    return (unsigned short)(r >> 16);
}

__device__ __forceinline__ void lds_load16(const void* g, void* l) {
    __builtin_amdgcn_global_load_lds(
        (const __attribute__((address_space(1))) uint32_t*)g,
        (__attribute__((address_space(3))) uint32_t*)l, 16, 0, 0);
}

// ---------- kernel 1 (tiny): x -> bf16 only (1024 rows; q2 for ALL rows comes from the GEMM) ----------
__global__ __launch_bounds__(256) void convert_x(const float* __restrict__ x,
                                                 unsigned short* __restrict__ x_bf) {
    int wave = threadIdx.x >> 6, lane = threadIdx.x & 63;
    int r = blockIdx.x * 4 + wave;  // 0..1023
    float4 v = ((const float4*)(x + (size_t)r * FEAT))[lane];
    ushort4 h;
    h.x = f2bf(v.x); h.y = f2bf(v.y); h.z = f2bf(v.z); h.w = f2bf(v.w);
    ((ushort4*)x_bf)[(size_t)r * 64 + lane] = h;
}

// ---------- kernel 2: fused convert(A)+GEMM. One block = 64 q-rows x ALL 1024 x-cols ----------
// A staged once f32->bf16 into swizzled LDS (granule g of row r at phys (g&24)|((g&7)^(r&7)),
// so ds_read_b128 of a column-slice spreads across banks); q2 computed during conversion.
// B (x_bf) pipelined per 32-feat chunk: double-buffered global_load_lds, counted vmcnt(2),
// raw s_barrier (prefetch stays in flight across barriers), setprio around MFMA.
// Per-gx epilogue is register-only (wave owns all 64 rows of its 32 cols -> quad shuffle merge).
__global__ __launch_bounds__(256, 3) void nn_fused(const float* __restrict__ x,
                                                   const float* __restrict__ queue,
                                                   const unsigned short* __restrict__ x_bf,
                                                   float* __restrict__ q2,
                                                   uint2* __restrict__ partials) {
    __shared__ __align__(16) unsigned short As[BM * FEAT];    // 32 KB, full A tile, swizzled
    __shared__ __align__(16) unsigned short Bs[2][128 * 32];  // 2 x 8 KB, B chunk dbuf
    __shared__ __align__(16) float sq2[BM];

    const int t    = threadIdx.x;
    const int w    = t >> 6, lane = t & 63;
    const int quad = lane >> 4, l16 = lane & 15;
    const int gy   = blockIdx.x;

    // ---- issue B stage(0) first: DMA overlaps the A conversion below ----
    const int srow = lane >> 2;                        // row within 16-row group
    const int sgl  = (lane & 3) ^ ((lane >> 3) & 3);   // pre-swizzled source granule
    const unsigned short* gB0 = x_bf + (size_t)(w * 32 + srow) * FEAT + sgl * 8;
    lds_load16(gB0,             &Bs[0][(w * 32) * 32]);
    lds_load16(gB0 + 16 * FEAT, &Bs[0][(w * 32 + 16) * 32]);

    // ---- A stage: 64 rows f32 -> bf16 swizzled LDS, q2 on the fly ----
    const int arow = t >> 2, aqtr = t & 3;             // 4 threads per row, 64 feats each
    const float* asrc = q_row_ptr(gy * BM + arow, x, queue) + aqtr * 64;
    float ss = 0.0f;
#pragma unroll
    for (int gi = 0; gi < 8; ++gi) {                   // 8 granules of 8 feats
        float4 a = *(const float4*)(asrc + gi * 8);
        float4 b = *(const float4*)(asrc + gi * 8 + 4);
        ss += a.x * a.x + a.y * a.y + a.z * a.z + a.w * a.w
            + b.x * b.x + b.y * b.y + b.z * b.z + b.w * b.w;
        uint32_t p0 = (uint32_t)f2bf(a.x) | ((uint32_t)f2bf(a.y) << 16);
        uint32_t p1 = (uint32_t)f2bf(a.z) | ((uint32_t)f2bf(a.w) << 16);
        uint32_t p2 = (uint32_t)f2bf(b.x) | ((uint32_t)f2bf(b.y) << 16);
        uint32_t p3 = (uint32_t)f2bf(b.z) | ((uint32_t)f2bf(b.w) << 16);
        const int g    = aqtr * 8 + gi;
        const int phys = (g & 24) | ((g & 7) ^ (arow & 7));
        *(uint4*)&As[arow * FEAT + phys * 8] = make_uint4(p0, p1, p2, p3);
    }
    ss += __shfl_xor(ss, 1, 64);                       // combine the 4 quarter-sums
    ss += __shfl_xor(ss, 2, 64);
    if (aqtr == 0) { sq2[arow] = ss; q2[gy * BM + arow] = ss; }

    v4f acc[4][2];                                     // [tm: 4 q sub-rows][tn: 2 x sub-cols]
#pragma unroll
    for (int a = 0; a < 4; ++a)
#pragma unroll
        for (int b = 0; b < 2; ++b) acc[a][b] = (v4f)0.0f;

    // read-side bases: wave owns cols [w*32, w*32+32) of each x-tile, all 64 A rows
    const int  gphysB = quad ^ ((l16 >> 1) & 3);
    const char* Brd = (const char*)&Bs[0][0] + (size_t)(w * 32 + l16) * 64 + gphysB * 16;

    __syncthreads();   // A LDS ready for all waves; drains stage(0)

    for (int gx = 0; gx < 8; ++gx) {
#pragma unroll
        for (int c = 0; c < 8; ++c) {                  // 8 x 32-feat chunks
            const int m = gx * 8 + c;
            if (m < 63) {                              // prefetch chunk m+1 into buf (c+1)&1
                const int mm = m + 1;
                const unsigned short* gBn = gB0 + (size_t)(mm >> 3) * (128 * FEAT) + (mm & 7) * 32;
                unsigned short* dstb = &Bs[(c + 1) & 1][(w * 32) * 32];
                lds_load16(gBn,             dstb);
                lds_load16(gBn + 16 * FEAT, dstb + 16 * 32);
                __builtin_amdgcn_sched_barrier(0);
                asm volatile("s_waitcnt vmcnt(2)" ::: "memory");  // stage(m) done, m+1 in flight
            } else {
                __builtin_amdgcn_sched_barrier(0);
                asm volatile("s_waitcnt vmcnt(0)" ::: "memory");
            }
            __builtin_amdgcn_s_barrier();              // raw: no vmcnt drain

            // A granule for this chunk: g = c*4+quad, phys = (g&24)|((g&7)^(row&7)), row&7==l16&7
            const int physA = ((c >> 1) * 8) | ((((c & 1) * 4) + quad) ^ (l16 & 7));
            v8s fa[4], fb[2];
#pragma unroll
            for (int tm = 0; tm < 4; ++tm)
                fa[tm] = *(const v8s*)((const char*)As + (size_t)(tm * 16 + l16) * 512 + physA * 16);
            const char* Bc = Brd + (c & 1) * 8192;
#pragma unroll
            for (int tn = 0; tn < 2; ++tn)
                fb[tn] = *(const v8s*)(Bc + tn * 1024);
            __builtin_amdgcn_s_setprio(1);
#pragma unroll
            for (int tm = 0; tm < 4; ++tm)
#pragma unroll
                for (int tn = 0; tn < 2; ++tn)
                    acc[tm][tn] = __builtin_amdgcn_mfma_f32_16x16x32_bf16(fa[tm], fb[tn], acc[tm][tn], 0, 0, 0);
            __builtin_amdgcn_s_setprio(0);
            __builtin_amdgcn_s_barrier();              // close reads of this buf before restage
        }

        // ---- per-gx epilogue: register-only, no block barrier ----
        float q2r[4][4];
#pragma unroll
        for (int tm = 0; tm < 4; ++tm) {
            v4f qq = *(const v4f*)&sq2[tm * 16 + quad * 4];
#pragma unroll
            for (int r = 0; r < 4; ++r) q2r[tm][r] = qq[r];
        }
        const int jbase = gy * BM + quad * 4;
#pragma unroll
        for (int tn = 0; tn < 2; ++tn) {
            uint32_t k1 = 0xFFFFFFFFu, k2 = 0xFFFFFFFFu;
#pragma unroll
            for (int tm = 0; tm < 4; ++tm)
#pragma unroll
                for (int r = 0; r < 4; ++r) {
                    float mv = fmaf(-2.0f, acc[tm][tn][r], q2r[tm][r]);
                    uint32_t u = key_flip(__float_as_uint(mv));
                    uint32_t key = (u & 0xFFFF8000u) | (uint32_t)(jbase + tm * 16 + r);
                    k2_insert(k1, k2, key);
                    acc[tm][tn][r] = 0.0f;             // reset for next gx
                }
            // merge across quads (same x-col lives in lanes l16, +16, +32, +48)
#pragma unroll
            for (int mask = 16; mask <= 32; mask <<= 1) {
                uint32_t o1 = __shfl_xor(k1, mask, 64);
                uint32_t o2 = __shfl_xor(k2, mask, 64);
                uint32_t hi = max(k1, o1);
                k1 = min(k1, o1);
                k2 = min(min(k2, o2), hi);
            }
            if (quad == 0)
                partials[(size_t)(gx * 128 + w * 32 + tn * 16 + l16) * NGY + gy] = make_uint2(k1, k2);
        }
    }
}

// ---------- kernel 3: key-based cutoff + exact f32 rescore + gather ----------
__global__ __launch_bounds__(256) void nn_finalize(const float* __restrict__ x,
                                                   const float* __restrict__ queue,
                                                   const float* __restrict__ q2,
                                                   const uint2* __restrict__ partials,
                                                   float* __restrict__ out) {
    __shared__ float    xs[256];
    __shared__ uint2    red[256];
    __shared__ int      list[64];
    __shared__ float    escore[64];
    __shared__ int      s_cnt;
    __shared__ uint32_t s_kcut;
    __shared__ int      s_j2;

    const int t = threadIdx.x, i = blockIdx.x;
    const int w = t >> 6, lane = t & 63;

    xs[t] = x[(size_t)i * FEAT + t];
    uint2 pa = partials[(size_t)i * NGY + t];
    uint2 pb = partials[(size_t)i * NGY + 256 + t];
    uint2 pm = k2_merge(pa, pb);   // merging preserves global-top2 candidacy
    red[t] = pm;
    if (t == 0) s_cnt = 0;
    __syncthreads();

    if (w == 0) {  // approx global top2 (keys) -> cutoff key
        uint2 a = red[lane];
        a = k2_merge(a, red[lane + 64]);
        a = k2_merge(a, red[lane + 128]);
        a = k2_merge(a, red[lane + 192]);
#pragma unroll
        for (int mask = 1; mask <= 32; mask <<= 1) {
            uint2 o;
            o.x = __shfl_xor(a.x, mask, 64);
            o.y = __shfl_xor(a.y, mask, 64);
            a = k2_merge(a, o);
        }
        if (lane == 0) {
            float cutf = key_m(a.y) + MARGIN;
            s_kcut = key_flip(__float_as_uint(cutf)) | 0x7FFFu;
        }
    }
    __syncthreads();
    uint32_t kcut = s_kcut;
    if (pm.x <= kcut) { int q_ = atomicAdd(&s_cnt, 1); if (q_ < 64) list[q_] = (int)(pm.x & 0x7FFFu); }
    if (pm.y <= kcut) { int q_ = atomicAdd(&s_cnt, 1); if (q_ < 64) list[q_] = (int)(pm.y & 0x7FFFu); }
    __syncthreads();
    int n = min(s_cnt, 64);

    for (int c = w; c < n; c += 4) {  // exact f32 rescore, one candidate per wave
        int j = list[c];
        const float4* qr = (const float4*)q_row_ptr(j, x, queue);
        float4 qv = qr[lane];
        float4 xv = ((const float4*)xs)[lane];
        float s = qv.x * xv.x + qv.y * xv.y + qv.z * xv.z + qv.w * xv.w;
#pragma unroll
        for (int off = 32; off; off >>= 1) s += __shfl_xor(s, off, 64);
        if (lane == 0) escore[c] = q2[j] - 2.0f * s;
    }
    __syncthreads();
    if (t == 0) {
        Top2 a;
        a.m1 = __builtin_inff(); a.j1 = 0x7FFFFFFF;
        a.m2 = __builtin_inff(); a.j2 = 0x7FFFFFFF;
        for (int c = 0; c < n; ++c) t2_insert(a, escore[c], list[c]);
        s_j2 = a.j2;  // second-nearest (nearest is self)
    }
    __syncthreads();
    out[(size_t)i * FEAT + t] = q_row_ptr(s_j2, x, queue)[t];
}

extern "C" void kernel_launch(void* const* d_in, const int* in_sizes, int n_in,
                              void* d_out, int out_size, void* d_ws, size_t ws_size,
                              hipStream_t stream) {
    const float* x     = (const float*)d_in[0];
    const float* queue = (const float*)d_in[1];

    unsigned short* x_bf     = (unsigned short*)d_ws;                    // 512 KB
    float*          q2       = (float*)((char*)d_ws + (1u << 20));       // 128 KB
    uint2*          partials = (uint2*)((char*)d_ws + (2u << 20));       // 4 MB

    convert_x<<<B_ROWS / 4, 256, 0, stream>>>(x, x_bf);
    nn_fused<<<NGY, 256, 0, stream>>>(x, queue, x_bf, q2, partials);
    nn_finalize<<<B_ROWS, 256, 0, stream>>>(x, queue, q2, partials, (float*)d_out);
}